// Round 1
// baseline (314.917 us; speedup 1.0000x reference)
//
#include <hip/hip_runtime.h>
#include <hip/hip_bf16.h>

#define NIN 64
#define NATT 64
#define NHEAD 4
#define D_K 16

// ---------------------------------------------------------------------------
// Kernel 1: fused QKV projection.
// Each block: 256 threads = 4 nodes x 64 output columns.
// q,k written in flat [N,64] layout (head-major: col = h*16+d).
// v written directly to output in [N, D_K, NHEAD] layout: n*64 + d*4 + h.
// ---------------------------------------------------------------------------
__global__ __launch_bounds__(256) void qkv_kernel(
    const float* __restrict__ x,
    const float* __restrict__ Wq, const float* __restrict__ bq,
    const float* __restrict__ Wk, const float* __restrict__ bk,
    const float* __restrict__ Wv, const float* __restrict__ bv,
    float* __restrict__ qout, float* __restrict__ kout,
    float* __restrict__ vout, int n_nodes) {
  __shared__ float xs[4][64];
  const int t = threadIdx.x;        // 0..255
  const int g = t >> 6;             // node sub-index 0..3
  const int c = t & 63;             // output column
  const int node = blockIdx.x * 4 + g;
  if (node < n_nodes) xs[g][c] = x[node * 64 + c];
  __syncthreads();
  if (node >= n_nodes) return;

  float accq = bq[c];
  float acck = bk[c];
  float accv = bv[c];
#pragma unroll 16
  for (int r = 0; r < 64; ++r) {
    const float xv = xs[g][r];
    accq = fmaf(xv, Wq[r * 64 + c], accq);
    acck = fmaf(xv, Wk[r * 64 + c], acck);
    accv = fmaf(xv, Wv[r * 64 + c], accv);
  }
  qout[node * 64 + c] = accq;
  kout[node * 64 + c] = acck;
  // v output transposed per node: [d_k, nhead]; col c = h*16 + d
  vout[node * 64 + (c & 15) * 4 + (c >> 4)] = accv;
}

// ---------------------------------------------------------------------------
// Kernel 2: per-edge head dots, exp, denominator atomics.
// 16 lanes per edge: lane s in [0,16) loads float4 #s of q[src] and k[dst]
// rows (fully coalesced 256B per row). Head h = s>>2; 4-lane shfl_xor reduce.
// Lanes s<4 write prods[e][s], ex -> attn slot, atomicAdd denom[src][s].
// No max-subtraction: exp(p)/sum(exp(p)) == softmax (p is O(1), fp32-safe).
// ---------------------------------------------------------------------------
__global__ __launch_bounds__(256) void edge_kernel(
    const int* __restrict__ edge0, const int* __restrict__ edge1,
    const float4* __restrict__ q, const float4* __restrict__ k,
    float* __restrict__ prods, float* __restrict__ attn,
    float* __restrict__ denom, int n_edges) {
  const long long tid = (long long)blockIdx.x * blockDim.x + threadIdx.x;
  const int e = (int)(tid >> 4);
  const int s = (int)(tid & 15);
  if (e >= n_edges) return;
  const int src = edge0[e];
  const int dst = edge1[e];

  const float4 a = q[(long long)src * 16 + s];
  const float4 b = k[(long long)dst * 16 + s];
  float d = a.x * b.x + a.y * b.y + a.z * b.z + a.w * b.w;
  // reduce over the 4 lanes of each head (lanes differ only in bits [1:0])
  d += __shfl_xor(d, 1);
  d += __shfl_xor(d, 2);
  d *= 0.25f;  // 1/sqrt(16)

  // head h's value lives in lanes (group_base + 4h .. +3). Lane s<4 fetches head s.
  const int l = threadIdx.x & 63;
  const float pv = __shfl(d, (l & ~15) + (l & 3) * 4);

  if (s < 4) {
    prods[(long long)e * 4 + s] = pv;
    const float ex = expf(pv);
    attn[(long long)e * 4 + s] = ex;  // un-normalized; kernel 3 divides
    atomicAdd(&denom[src * 4 + s], ex);
  }
}

// ---------------------------------------------------------------------------
// Kernel 3: normalize attention in-place: attn /= (denom[seg] + 1e-16).
// One thread per (edge, head).
// ---------------------------------------------------------------------------
__global__ __launch_bounds__(256) void norm_kernel(
    const int* __restrict__ edge0, const float* __restrict__ denom,
    float* __restrict__ attn, long long n4) {
  const long long i = (long long)blockIdx.x * blockDim.x + threadIdx.x;
  if (i >= n4) return;
  const int e = (int)(i >> 2);
  const int h = (int)(i & 3);
  const int seg = edge0[e];
  attn[i] = attn[i] / (denom[seg * 4 + h] + 1e-16f);
}

extern "C" void kernel_launch(void* const* d_in, const int* in_sizes, int n_in,
                              void* d_out, int out_size, void* d_ws, size_t ws_size,
                              hipStream_t stream) {
  const float* x  = (const float*)d_in[0];
  const int* edge = (const int*)d_in[1];
  const float* Wq = (const float*)d_in[2];
  const float* bq = (const float*)d_in[3];
  const float* Wk = (const float*)d_in[4];
  const float* bk = (const float*)d_in[5];
  const float* Wv = (const float*)d_in[6];
  const float* bv = (const float*)d_in[7];

  const int n_nodes = in_sizes[0] / NIN;       // 50000
  const int n_edges = in_sizes[1] / 2;         // 1600000
  const int* edge0 = edge;                     // [E] source (seg idx)
  const int* edge1 = edge + n_edges;           // [E] destination

  // Output layout: attention [E*4] | v [N*64] | prods [E*4]
  float* out_attn  = (float*)d_out;
  float* out_v     = out_attn + (long long)n_edges * NHEAD;
  float* out_prods = out_v + (long long)n_nodes * NATT;

  // Workspace: q [N*64] | k [N*64] | denom [N*4]
  float* ws_q     = (float*)d_ws;
  float* ws_k     = ws_q + (long long)n_nodes * NATT;
  float* ws_denom = ws_k + (long long)n_nodes * NATT;

  hipMemsetAsync(ws_denom, 0, (size_t)n_nodes * NHEAD * sizeof(float), stream);

  {
    const int blocks = (n_nodes + 3) / 4;
    qkv_kernel<<<blocks, 256, 0, stream>>>(x, Wq, bq, Wk, bk, Wv, bv,
                                           ws_q, ws_k, out_v, n_nodes);
  }
  {
    const long long total = (long long)n_edges * 16;
    const int blocks = (int)((total + 255) / 256);
    edge_kernel<<<blocks, 256, 0, stream>>>(edge0, edge1,
                                            (const float4*)ws_q, (const float4*)ws_k,
                                            out_prods, out_attn, ws_denom, n_edges);
  }
  {
    const long long n4 = (long long)n_edges * NHEAD;
    const int blocks = (int)((n4 + 255) / 256);
    norm_kernel<<<blocks, 256, 0, stream>>>(edge0, ws_denom, out_attn, n4);
  }
}

// Round 3
// 218.719 us; speedup vs baseline: 1.4398x; 1.4398x over previous
//
#include <hip/hip_runtime.h>
#include <hip/hip_bf16.h>

#define NHEAD 4

typedef __hip_bfloat16 bf16;
typedef __hip_bfloat162 bf162;

// ---------------------------------------------------------------------------
// Kernel 1: fused QKV projection. 256 threads = 4 waves; block handles 16
// nodes (wave qg owns nodes qg*4..qg*4+3). Each W element loaded once per
// thread feeds 4 FMAs (4 nodes) -> 4x less W cache traffic than R0.
// q,k stored bf16 [N,64] (col = h*16+d). v fp32 direct to out, [N, d, h].
// ---------------------------------------------------------------------------
__global__ __launch_bounds__(256) void qkv_kernel(
    const float* __restrict__ x,
    const float* __restrict__ Wq, const float* __restrict__ bq,
    const float* __restrict__ Wk, const float* __restrict__ bk,
    const float* __restrict__ Wv, const float* __restrict__ bv,
    bf16* __restrict__ qout, bf16* __restrict__ kout,
    float* __restrict__ vout, int n_nodes) {
  __shared__ float xs[16][64];
  const int t = threadIdx.x;
  const int base = blockIdx.x * 16;
#pragma unroll
  for (int j = 0; j < 4; ++j) {
    const int idx = t + 256 * j;
    const int nn = idx >> 6, cc = idx & 63;
    xs[nn][cc] = (base + nn < n_nodes) ? x[(size_t)(base + nn) * 64 + cc] : 0.f;
  }
  __syncthreads();
  const int c = t & 63;
  const int qg = t >> 6;  // wave id

  float aq[4], ak[4], av[4];
  const float bqv = bq[c], bkv = bk[c], bvv = bv[c];
#pragma unroll
  for (int j = 0; j < 4; ++j) { aq[j] = bqv; ak[j] = bkv; av[j] = bvv; }

#pragma unroll 4
  for (int r = 0; r < 64; ++r) {
    const float wq = Wq[r * 64 + c];
    const float wk = Wk[r * 64 + c];
    const float wv = Wv[r * 64 + c];
#pragma unroll
    for (int j = 0; j < 4; ++j) {
      const float xv = xs[qg * 4 + j][r];  // wave-uniform addr -> LDS broadcast
      aq[j] = fmaf(xv, wq, aq[j]);
      ak[j] = fmaf(xv, wk, ak[j]);
      av[j] = fmaf(xv, wv, av[j]);
    }
  }
#pragma unroll
  for (int j = 0; j < 4; ++j) {
    const int node = base + qg * 4 + j;
    if (node < n_nodes) {
      qout[(size_t)node * 64 + c] = __float2bfloat16(aq[j]);
      kout[(size_t)node * 64 + c] = __float2bfloat16(ak[j]);
      vout[(size_t)node * 64 + (c & 15) * 4 + (c >> 4)] = av[j];
    }
  }
}

// ---------------------------------------------------------------------------
// Kernel 2: per-(edge,head) dot + denominator atomics.
// Thread i: e = i>>2, h = i&3. Loads head h's 32B slice of bf16 q[src] and
// k[dst] rows (2x uint4 each), full 16-dim dot in-lane (no shuffles).
// prods writes are 256B-contiguous per wave. attn NOT written here -- norm
// recomputes exp(prods) (saves a 25.6MB store).
// ---------------------------------------------------------------------------
__device__ __forceinline__ float dot8(uint4 a, uint4 b) {
  const unsigned* pa = &a.x;
  const unsigned* pb = &b.x;
  float acc = 0.f;
#pragma unroll
  for (int i = 0; i < 4; ++i) {
    const float2 fa = __bfloat1622float2(*(const bf162*)&pa[i]);
    const float2 fb = __bfloat1622float2(*(const bf162*)&pb[i]);
    acc = fmaf(fa.x, fb.x, acc);
    acc = fmaf(fa.y, fb.y, acc);
  }
  return acc;
}

__global__ __launch_bounds__(256) void edge_kernel(
    const int* __restrict__ edge0, const int* __restrict__ edge1,
    const uint4* __restrict__ q, const uint4* __restrict__ k,
    float* __restrict__ prods, float* __restrict__ denom, int n_edges) {
  const long long i = (long long)blockIdx.x * 256 + threadIdx.x;
  const int e = (int)(i >> 2);
  const int h = (int)(i & 3);
  if (e >= n_edges) return;
  const int src = edge0[e];
  const int dst = edge1[e];

  // bf16 row = 128B = 8 uint4; head h = slots 2h, 2h+1
  const uint4 a0 = q[(size_t)src * 8 + h * 2];
  const uint4 a1 = q[(size_t)src * 8 + h * 2 + 1];
  const uint4 b0 = k[(size_t)dst * 8 + h * 2];
  const uint4 b1 = k[(size_t)dst * 8 + h * 2 + 1];

  const float p = (dot8(a0, b0) + dot8(a1, b1)) * 0.25f;  // 1/sqrt(16)
  prods[i] = p;
  atomicAdd(&denom[src * 4 + h], __expf(p));
}

// ---------------------------------------------------------------------------
// Kernel 3: attn[i] = exp(prods[i]) / (denom[seg][h] + 1e-16)
// ---------------------------------------------------------------------------
__global__ __launch_bounds__(256) void norm_kernel(
    const int* __restrict__ edge0, const float* __restrict__ denom,
    const float* __restrict__ prods, float* __restrict__ attn, long long n4) {
  const long long i = (long long)blockIdx.x * 256 + threadIdx.x;
  if (i >= n4) return;
  const int e = (int)(i >> 2);
  const int h = (int)(i & 3);
  const int seg = edge0[e];
  attn[i] = __expf(prods[i]) / (denom[seg * 4 + h] + 1e-16f);
}

extern "C" void kernel_launch(void* const* d_in, const int* in_sizes, int n_in,
                              void* d_out, int out_size, void* d_ws, size_t ws_size,
                              hipStream_t stream) {
  const float* x  = (const float*)d_in[0];
  const int* edge = (const int*)d_in[1];
  const float* Wq = (const float*)d_in[2];
  const float* bq = (const float*)d_in[3];
  const float* Wk = (const float*)d_in[4];
  const float* bk = (const float*)d_in[5];
  const float* Wv = (const float*)d_in[6];
  const float* bv = (const float*)d_in[7];

  const int n_nodes = in_sizes[0] / 64;   // 50000
  const int n_edges = in_sizes[1] / 2;    // 1600000
  const int* edge0 = edge;
  const int* edge1 = edge + n_edges;

  // Output: attention [E*4] | v [N*64] | prods [E*4]
  float* out_attn  = (float*)d_out;
  float* out_v     = out_attn + (long long)n_edges * NHEAD;
  float* out_prods = out_v + (long long)n_nodes * 64;

  // Workspace: q bf16 [N*64] | k bf16 [N*64] | denom f32 [N*4]
  bf16* ws_q = (bf16*)d_ws;
  bf16* ws_k = ws_q + (size_t)n_nodes * 64;
  float* ws_denom = (float*)(ws_k + (size_t)n_nodes * 64);

  hipMemsetAsync(ws_denom, 0, (size_t)n_nodes * NHEAD * sizeof(float), stream);

  {
    const int blocks = (n_nodes + 15) / 16;
    qkv_kernel<<<blocks, 256, 0, stream>>>(x, Wq, bq, Wk, bk, Wv, bv,
                                           ws_q, ws_k, out_v, n_nodes);
  }
  {
    const long long total = (long long)n_edges * NHEAD;
    const int blocks = (int)((total + 255) / 256);
    edge_kernel<<<blocks, 256, 0, stream>>>(edge0, edge1,
                                            (const uint4*)ws_q, (const uint4*)ws_k,
                                            out_prods, ws_denom, n_edges);
    norm_kernel<<<blocks, 256, 0, stream>>>(edge0, ws_denom, out_prods,
                                            out_attn, total);
  }
}